// Round 7
// baseline (227.632 us; speedup 1.0000x reference)
//
#include <hip/hip_runtime.h>

#define N 256
#define C 128
#define H 4
#define D 32
#define NP (N*N)            // 65536 pairs
#define LN_EPS 1e-5f
#define LOG2E 1.4426950408889634f

// Raw workgroup barrier: LDS ordering only (stores keep flying).
__device__ __forceinline__ void barrier_lgkm() {
    __asm__ volatile("s_waitcnt lgkmcnt(0)" ::: "memory");
    __builtin_amdgcn_sched_barrier(0);
    __builtin_amdgcn_s_barrier();
    __builtin_amdgcn_sched_barrier(0);
}
__device__ __forceinline__ void drain_lds() {
    __asm__ volatile("s_waitcnt lgkmcnt(0)" ::: "memory");
    __builtin_amdgcn_sched_barrier(0);
}

using f32x4 = __attribute__((ext_vector_type(4))) float;
using bf8   = __attribute__((ext_vector_type(8))) short;   // 8 x bf16 (4 VGPRs)
using u16x4 = __attribute__((ext_vector_type(4))) unsigned short;

__device__ __forceinline__ float bf2f(ushort u) {
    union { uint u; float f; } v; v.u = ((uint)u) << 16; return v.f;
}
__device__ __forceinline__ ushort f2bf(float f) {           // RNE
    union { float f; uint u; } v; v.f = f;
    uint u = v.u;
    u += 0x7fffu + ((u >> 16) & 1u);
    return (ushort)(u >> 16);
}
__device__ __forceinline__ ushort f2bf_trunc(float f) {     // truncate
    union { float f; uint u; } v; v.f = f;
    return (ushort)(v.u >> 16);
}

// ---------------------------------------------------------------- weights
// q-scale folds 1/sqrt(D) AND log2e (softmax uses exp2 directly).
__global__ __launch_bounds__(256) void prep_weights(
    const float* __restrict__ wq, const float* __restrict__ wk,
    const float* __restrict__ wv, const float* __restrict__ wg,
    const float* __restrict__ wo,
    ushort* __restrict__ Wcat, ushort* __restrict__ Wo)
{
    int t = blockIdx.x * 256 + threadIdx.x;    // 65536 threads
    const float scale = 0.17677669529663689f * LOG2E;
    float v;
    if (t < 16384)       v = wq[t] * scale;
    else if (t < 32768)  v = wk[t - 16384];
    else if (t < 49152)  v = wv[t - 32768];
    else                 v = wg[t - 49152];
    Wcat[t] = f2bf(v);
    if (t < 16384) Wo[t] = f2bf(wo[t]);
}

// ---------------------------------------------------------------- LN + triangle bias
// Computes tri[h,q,k] = wb_h . LN(x[q,k]) in fp32, scattered into the
// pre-permuted attn fragment layout. 32 lanes per pair (4 ch each); LN and
// the 4 head-dots are butterfly shfl reduces within the 32-lane group.
__global__ __launch_bounds__(256) void ln_tri(
    const float* __restrict__ x, const float* __restrict__ lnw,
    const float* __restrict__ lnb, const float* __restrict__ wb,
    ushort* __restrict__ tri_p)
{
    int t = threadIdx.x;
    int wave = t >> 6, lane = t & 63;
    int lane32 = lane & 31, rsel = lane >> 5;
    const float4 w4 = ((const float4*)lnw)[lane32];
    const float4 b4 = ((const float4*)lnb)[lane32];
    float4 wb0 = ((const float4*)(wb      ))[lane32];
    float4 wb1 = ((const float4*)(wb + 128))[lane32];
    float4 wb2 = ((const float4*)(wb + 256))[lane32];
    float4 wb3 = ((const float4*)(wb + 384))[lane32];

    #pragma unroll 1
    for (int pp = 0; pp < 8; pp++) {
        int p = blockIdx.x * 64 + pp * 8 + wave * 2 + rsel;
        float4 v = ((const float4*)(x + (size_t)p * C))[lane32];
        float s  = v.x + v.y + v.z + v.w;
        float ss = v.x*v.x + v.y*v.y + v.z*v.z + v.w*v.w;
        #pragma unroll
        for (int m = 1; m < 32; m <<= 1) {
            s  += __shfl_xor(s, m, 64);
            ss += __shfl_xor(ss, m, 64);
        }
        float mean = s * (1.f / 128.f);
        float var  = ss * (1.f / 128.f) - mean * mean;
        float rstd = rsqrtf(var + LN_EPS);
        float x0 = (v.x - mean) * rstd * w4.x + b4.x;
        float x1 = (v.y - mean) * rstd * w4.y + b4.y;
        float x2 = (v.z - mean) * rstd * w4.z + b4.z;
        float x3 = (v.w - mean) * rstd * w4.w + b4.w;
        float a0 = x0*wb0.x + x1*wb0.y + x2*wb0.z + x3*wb0.w;
        float a1 = x0*wb1.x + x1*wb1.y + x2*wb1.z + x3*wb1.w;
        float a2 = x0*wb2.x + x1*wb2.y + x2*wb2.z + x3*wb2.w;
        float a3 = x0*wb3.x + x1*wb3.y + x2*wb3.z + x3*wb3.w;
        #pragma unroll
        for (int m = 1; m < 32; m <<= 1) {
            a0 += __shfl_xor(a0, m, 64);
            a1 += __shfl_xor(a1, m, 64);
            a2 += __shfl_xor(a2, m, 64);
            a3 += __shfl_xor(a3, m, 64);
        }
        if (lane32 < 4) {
            float av = (lane32 == 0) ? a0 : (lane32 == 1) ? a1
                     : (lane32 == 2) ? a2 : a3;
            int q = p >> 8, k = p & 255;
            int qc = q >> 4, quadq = (q >> 2) & 3, rr = q & 3;
            int n = k >> 4, lk = k & 15;
            int lanet = quadq * 16 + lk;
            int v2 = n * 4 + rr, j = v2 >> 3, m2 = v2 & 7;
            tri_p[lane32 * 65536 + ((qc * 8 + j) * 64 + lanet) * 8 + m2] =
                f2bf(av * LOG2E);
        }
    }
}

// ---------------------------------------------------------------- row-fused everything
// One 1024-thread block (16 waves) per attention row i. LN -> Xn (LDS, 64KB).
// Per head: project K/V/Q/gate via MFMA (shared A-frags from Xn), scatter
// K/V directly into the verified attn fragment layouts in LDS, Q transposed
// through the per-wave P buffer, gate in registers; then QK^T -> exp2 ->
// PV (64-key quarter P bufs) -> fused out-proj into persistent oacc.
// q/k/v/gate/O never touch global memory.
__global__ __launch_bounds__(1024, 4) void row_fused(
    const float* __restrict__ x, const float* __restrict__ lnw,
    const float* __restrict__ lnb, const ushort* __restrict__ Wcat,
    const float* __restrict__ bg, const ushort* __restrict__ tri_p,
    const float* __restrict__ mask, const ushort* __restrict__ Wo,
    const float* __restrict__ bo, float* __restrict__ out)
{
    __shared__ ushort Xn[256 * 128];   // 64 KB, swizzled LN output (row-persistent)
    __shared__ ushort Kf[8192];        // 16 KB, K fragments (attn-read layout)
    __shared__ ushort Vf[8192];        // 16 KB, V fragments (attn-read layout)
    __shared__ ushort Pf[16 * 1024];   // 32 KB, per-wave 2KB P/transpose buffer
    __shared__ float  Ml[256];         // 1 KB, pre-scaled mask bias

    int i = blockIdx.x;
    int t = threadIdx.x;
    int wave = t >> 6, lane = t & 63;
    int lane32 = lane & 31, rsel = lane >> 5;
    int lrow = lane & 15, quad = lane >> 4;

    // ---- phase 0: LN of the row's 256 pairs -> Xn; stage scaled mask
    {
        const float4 w4 = ((const float4*)lnw)[lane32];
        const float4 b4 = ((const float4*)lnb)[lane32];
        const float* xb = x + (size_t)i * N * C;
        if (t < 256) Ml[t] = (1e9f * LOG2E) * (mask[i * N + t] - 1.f);
        #pragma unroll
        for (int pp = 0; pp < 8; pp++) {
            int r = pp * 32 + wave * 2 + rsel;
            float4 v = ((const float4*)(xb + r * C))[lane32];
            float s  = v.x + v.y + v.z + v.w;
            float ss = v.x*v.x + v.y*v.y + v.z*v.z + v.w*v.w;
            #pragma unroll
            for (int m = 1; m < 32; m <<= 1) {
                s  += __shfl_xor(s, m, 64);
                ss += __shfl_xor(ss, m, 64);
            }
            float mean = s * (1.f / 128.f);
            float var  = ss * (1.f / 128.f) - mean * mean;
            float rstd = rsqrtf(var + LN_EPS);
            u16x4 o;
            o[0] = f2bf((v.x - mean) * rstd * w4.x + b4.x);
            o[1] = f2bf((v.y - mean) * rstd * w4.y + b4.y);
            o[2] = f2bf((v.z - mean) * rstd * w4.z + b4.z);
            o[3] = f2bf((v.w - mean) * rstd * w4.w + b4.w);
            int c8 = lane32 >> 1;
            int chunk = r * 16 + (c8 ^ (r & 7));
            *(u16x4*)&Xn[chunk * 8 + (lane32 & 1) * 4] = o;
        }
    }
    barrier_lgkm();

    f32x4 oacc[8];
    #pragma unroll
    for (int ct = 0; ct < 8; ct++) oacc[ct] = (f32x4){0.f, 0.f, 0.f, 0.f};

    ushort* Pw = Pf + wave * 1024;
    const int pq = quad * 32 + (lrow & 7);
    const int l3 = (lrow >> 3) & 1;

    #pragma unroll 1
    for (int h = 0; h < 4; h++) {
        // A-frags for this wave's 16-row strip (its 16 keys AND 16 queries)
        bf8 afr[4];
        #pragma unroll
        for (int ks = 0; ks < 4; ks++) {
            int row = wave * 16 + lrow;
            afr[ks] = *(const bf8*)&Xn[(row * 16 + ((ks * 4 + quad) ^ (row & 7))) * 8];
        }
        // ---- K,V,Q,gate projections: 32 MFMA sharing the same A-frags
        f32x4 qa[2], ka[2], va[2], ga[2];
        #pragma unroll
        for (int ni = 0; ni < 2; ni++) {
            qa[ni] = (f32x4){0.f,0.f,0.f,0.f}; ka[ni] = (f32x4){0.f,0.f,0.f,0.f};
            va[ni] = (f32x4){0.f,0.f,0.f,0.f}; ga[ni] = (f32x4){0.f,0.f,0.f,0.f};
        }
        const ushort* Wq_ = Wcat + (size_t)(h * 32) * C;
        const ushort* Wk_ = Wcat + (size_t)(128 + h * 32) * C;
        const ushort* Wv_ = Wcat + (size_t)(256 + h * 32) * C;
        const ushort* Wg_ = Wcat + (size_t)(384 + h * 32) * C;
        #pragma unroll
        for (int ks = 0; ks < 4; ks++) {
            #pragma unroll
            for (int ni = 0; ni < 2; ni++) {
                size_t ro = (size_t)(ni * 16 + lrow) * C + (ks * 4 + quad) * 8;
                qa[ni] = __builtin_amdgcn_mfma_f32_16x16x32_bf16(afr[ks], *(const bf8*)(Wq_ + ro), qa[ni], 0, 0, 0);
                ka[ni] = __builtin_amdgcn_mfma_f32_16x16x32_bf16(afr[ks], *(const bf8*)(Wk_ + ro), ka[ni], 0, 0, 0);
                va[ni] = __builtin_amdgcn_mfma_f32_16x16x32_bf16(afr[ks], *(const bf8*)(Wv_ + ro), va[ni], 0, 0, 0);
                ga[ni] = __builtin_amdgcn_mfma_f32_16x16x32_bf16(afr[ks], *(const bf8*)(Wg_ + ro), ga[ni], 0, 0, 0);
            }
        }
        barrier_lgkm();    // all waves finished reading prior head's Kf/Vf

        // ---- scatter K/V into the attn frag layouts; Q into per-wave buf.
        // C-layout: key/q = wave*16 + quad*4 + r, d = lrow + 16*ni.
        #pragma unroll
        for (int ni = 0; ni < 2; ni++) {
            int d = lrow + 16 * ni;
            #pragma unroll
            for (int r = 0; r < 4; r++) {
                int key = wave * 16 + quad * 4 + r;
                Kf[((key >> 4) * 64 + (d >> 3) * 16 + (key & 15)) * 8 + (d & 7)] =
                    f2bf(ka[ni][r]);
                Vf[((d >> 4) * 512 + (key >> 5) * 64 +
                    ((((key >> 3) & 3) * 16 + (d & 15)) ^ ((key >> 5) & 7))) * 8 +
                   (key & 7)] = f2bf(va[ni][r]);
                Pw[((d >> 3) * 16 + quad * 4 + r) * 8 + (d & 7)] = f2bf(qa[ni][r]);
            }
        }
        // gate sigmoid stays in registers (C-layout matches O's)
        float gr[2][4];
        {
            float gb0 = bg[h * 32 + lrow], gb1 = bg[h * 32 + 16 + lrow];
            #pragma unroll
            for (int ni = 0; ni < 2; ni++)
                #pragma unroll
                for (int r = 0; r < 4; r++)
                    gr[ni][r] = 1.f / (1.f + __expf(-(ga[ni][r] + (ni ? gb1 : gb0))));
        }
        barrier_lgkm();    // staging visible block-wide
        bf8 aq = *(const bf8*)&Pw[(quad * 16 + lrow) * 8];

        // ---- attention for this head
        float sum[4] = {0.f, 0.f, 0.f, 0.f};
        f32x4 o2[2];
        o2[0] = (f32x4){0.f,0.f,0.f,0.f};
        o2[1] = (f32x4){0.f,0.f,0.f,0.f};
        const ushort* trih = tri_p + (size_t)h * 65536;

        #pragma unroll
        for (int half = 0; half < 2; half++) {
            const ushort* tp = trih + ((size_t)(wave * 8 + half * 4) * 64 + lane) * 8;
            bf8 tf[4];
            #pragma unroll
            for (int jj = 0; jj < 4; jj++)
                tf[jj] = *(const bf8*)(tp + jj * 512);
            float mbh[8];
            #pragma unroll
            for (int j8 = 0; j8 < 8; j8++)
                mbh[j8] = Ml[(half * 8 + j8) * 16 + lrow];

            #pragma unroll
            for (int qq = 0; qq < 2; qq++) {
                #pragma unroll
                for (int j = 0; j < 4; j++) {
                    int n8h = qq * 4 + j;
                    bf8 kf = *(const bf8*)&Kf[((half * 8 + n8h) * 64 + lane) * 8];
                    f32x4 s = __builtin_amdgcn_mfma_f32_16x16x32_bf16(
                        aq, kf, (f32x4){0.f,0.f,0.f,0.f}, 0, 0, 0);
                    int pa = (j >> 1) * 512 + (((j << 1) + l3) & 3) * 128 + pq;
                    #pragma unroll
                    for (int r = 0; r < 4; r++) {
                        float tb = bf2f(((const ushort*)&tf[n8h >> 1])[((n8h & 1) << 2) + r]);
                        float e  = exp2f(s[r] + tb + mbh[n8h]);
                        sum[r]  += e;
                        Pw[pa + r * 8] = f2bf_trunc(e);
                    }
                }
                drain_lds();   // wave-private P visible; prior ap reads done
                __builtin_amdgcn_s_setprio(1);
                #pragma unroll
                for (int ksl = 0; ksl < 2; ksl++) {
                    bf8 ap = *(const bf8*)&Pw[(ksl * 64 + lane) * 8];
                    int ksg = half * 4 + qq * 2 + ksl;
                    #pragma unroll
                    for (int nv = 0; nv < 2; nv++) {
                        bf8 bv = *(const bf8*)&Vf[(nv * 512 + ksg * 64 + (lane ^ (ksg & 7))) * 8];
                        o2[nv] = __builtin_amdgcn_mfma_f32_16x16x32_bf16(ap, bv, o2[nv], 0, 0, 0);
                    }
                }
                __builtin_amdgcn_s_setprio(0);
            }
        }
        // ---- normalize + gate, transpose O to A-frag, fused out-proj
        #pragma unroll
        for (int r = 0; r < 4; r++) {
            float s = sum[r];
            s += __shfl_xor(s, 1, 64);
            s += __shfl_xor(s, 2, 64);
            s += __shfl_xor(s, 4, 64);
            s += __shfl_xor(s, 8, 64);
            sum[r] = 1.f / s;
        }
        #pragma unroll
        for (int nv = 0; nv < 2; nv++)
            #pragma unroll
            for (int r = 0; r < 4; r++) {
                float val = o2[nv][r] * sum[r] * gr[nv][r];
                Pw[(nv * 2 + l3) * 128 + pq + r * 8] = f2bf(val);
            }
        drain_lds();
        bf8 ap2 = *(const bf8*)&Pw[lane * 8];
        __builtin_amdgcn_s_setprio(1);
        #pragma unroll
        for (int ct = 0; ct < 8; ct++) {
            bf8 wv = *(const bf8*)(Wo + (size_t)(ct * 16 + lrow) * 128 + h * 32 + quad * 8);
            oacc[ct] = __builtin_amdgcn_mfma_f32_16x16x32_bf16(ap2, wv, oacc[ct], 0, 0, 0);
        }
        __builtin_amdgcn_s_setprio(0);
    }

    // ---- epilogue: + bias, fp32 stores
    #pragma unroll
    for (int ct = 0; ct < 8; ct++) {
        float bias = bo[ct * 16 + lrow];
        #pragma unroll
        for (int r = 0; r < 4; r++) {
            int qg = wave * 16 + quad * 4 + r;
            out[(size_t)(i * N + qg) * C + ct * 16 + lrow] = oacc[ct][r] + bias;
        }
    }
}

// ---------------------------------------------------------------- launch
extern "C" void kernel_launch(void* const* d_in, const int* in_sizes, int n_in,
                              void* d_out, int out_size, void* d_ws, size_t ws_size,
                              hipStream_t stream)
{
    const float* x    = (const float*)d_in[0];
    const float* mask = (const float*)d_in[1];
    const float* lnw  = (const float*)d_in[2];
    const float* lnb  = (const float*)d_in[3];
    const float* wb   = (const float*)d_in[4];
    const float* wq   = (const float*)d_in[5];
    const float* wk   = (const float*)d_in[6];
    const float* wv   = (const float*)d_in[7];
    const float* wg   = (const float*)d_in[8];
    const float* bg   = (const float*)d_in[9];
    const float* wo   = (const float*)d_in[10];
    const float* bo   = (const float*)d_in[11];
    float* out = (float*)d_out;

    uintptr_t w = (uintptr_t)d_ws;
    ushort* tri_p = (ushort*)w; w += (size_t)H * NP * 2;   // 0.5 MB
    ushort* Wcat  = (ushort*)w; w += 512 * 128 * 2;
    ushort* Wo    = (ushort*)w; w += 128 * 128 * 2;

    prep_weights<<<256, 256, 0, stream>>>(wq, wk, wv, wg, wo, Wcat, Wo);
    ln_tri<<<NP / 64, 256, 0, stream>>>(x, lnw, lnb, wb, tri_p);
    row_fused<<<N, 1024, 0, stream>>>(x, lnw, lnb, Wcat, bg, tri_p,
                                      mask, Wo, bo, out);
}